// Round 6
// baseline (70.922 us; speedup 1.0000x reference)
//
#include <hip/hip_runtime.h>
#include <hip/hip_bf16.h>

#define NTOK 4096
#define BATCH 8
#define NROWS (BATCH * NTOK)   // 32768

typedef __attribute__((ext_vector_type(8))) short bfx8;
typedef __attribute__((ext_vector_type(4))) short bfx4;
typedef __attribute__((ext_vector_type(4))) float f32x4;

__device__ __forceinline__ short f2bf(float f) {
    unsigned u = __builtin_bit_cast(unsigned, f);
    u += 0x7fffu + ((u >> 16) & 1u);
    return (short)(u >> 16);
}
__device__ __forceinline__ unsigned pk2(float a, float b) {
    return (unsigned)(unsigned short)f2bf(a) | ((unsigned)(unsigned short)f2bf(b) << 16);
}

#define MFMA16(a, b, c) __builtin_amdgcn_mfma_f32_16x16x32_bf16(a, b, c, 0, 0, 0)
#define LGKM0()                                              \
    do {                                                     \
        asm volatile("s_waitcnt lgkmcnt(0)" ::: "memory");   \
        __builtin_amdgcn_sched_barrier(0);                   \
    } while (0)

// ---------------- weight prep: WT[co][ci] = bf16(scale * g[ci] * W[ci][co]) ----------------
__global__ __launch_bounds__(256) void prep_w(
    const float* __restrict__ Wq, const float* __restrict__ Wk,
    const float* __restrict__ Wv, const float* __restrict__ Wp,
    const float* __restrict__ qg, const float* __restrict__ qb,
    const float* __restrict__ kg, const float* __restrict__ kb,
    const float* __restrict__ vg, const float* __restrict__ vb,
    short* __restrict__ wt, float* __restrict__ bbp) {
    int m = blockIdx.x;
    int ci0 = blockIdx.y * 16;
    const float *W, *g, *be;
    float scale = 1.0f;
    if (m == 0)      { W = Wq; g = qg; be = qb; scale = 0.17677669529663687f; }
    else if (m == 1) { W = Wk; g = kg; be = kb; }
    else if (m == 2) { W = Wv; g = vg; be = vb; }
    else             { W = Wp; g = nullptr; be = nullptr; }
    __shared__ float tile[16][257];
    int t = threadIdx.x;
#pragma unroll
    for (int i = 0; i < 16; i++)
        tile[i][t] = W[(size_t)(ci0 + i) * 256 + t];
    __syncthreads();
    float p = 0.f;
    if (be) {
#pragma unroll
        for (int i = 0; i < 16; i++) p += be[ci0 + i] * tile[i][t];
    }
    bbp[(m * 16 + blockIdx.y) * 256 + t] = p;
    short* WT = wt + m * 65536 + t * 256 + ci0;
    bfx8 o0, o1;
#pragma unroll
    for (int j = 0; j < 8; j++) {
        float gv = g ? g[ci0 + j] : 1.0f;
        o0[j] = f2bf(scale * gv * tile[j][t]);
    }
#pragma unroll
    for (int j = 0; j < 8; j++) {
        float gv = g ? g[ci0 + 8 + j] : 1.0f;
        o1[j] = f2bf(scale * gv * tile[8 + j][t]);
    }
    *reinterpret_cast<bfx8*>(WT) = o0;
    *reinterpret_cast<bfx8*>(WT + 8) = o1;
}

__global__ __launch_bounds__(256) void prep_b(
    const float* __restrict__ bq, const float* __restrict__ bk,
    const float* __restrict__ bv, const float* __restrict__ bp,
    const float* __restrict__ bbp, float* __restrict__ bb) {
    int m = blockIdx.x, t = threadIdx.x;
    const float* bias = (m == 0) ? bq : (m == 1) ? bk : (m == 2) ? bv : bp;
    float scale = (m == 0) ? 0.17677669529663687f : 1.0f;
    float s = bias[t];
#pragma unroll
    for (int i = 0; i < 16; i++) s += bbp[(m * 16 + i) * 256 + t];
    bb[m * 256 + t] = scale * s;
}

// ---------------- mega kernel: LN + qkv GEMM + attention + projection ----------------
// 512 blocks (b, chunk) x 512 threads (8 waves; wave = head = 32-col strip).
// Shared A slot (pitch 264): cva_hat -> xs_hat -> o_s.
// Per-wave 5120B scratch: q^T -> k^T -> V^T -> P^T halves -> trw epilogue.
// Attention in S^T orientation: S^T = mfma(K,Q^T); O^T = mfma(V^T,P^T).
__global__ __launch_bounds__(512, 4) void mega(const float* __restrict__ x,
                                               const float* __restrict__ cva,
                                               const short* __restrict__ wt,
                                               const float* __restrict__ bb,
                                               float* __restrict__ out) {
    int id = blockIdx.x;
    int b = id >> 6, ch = id & 63;
    int t = threadIdx.x, w = t >> 6, l = t & 63, c = l & 15, g = l >> 4;

    __shared__ short A[64 * 264];       // 33792 B
    __shared__ short scr_[8][2560];     // 40960 B (5120 B per wave)
    __shared__ float red[8][64][2];     // 4096 B
    short* S = scr_[w];

    const float* xb   = x + (size_t)b * 1048576 + ch * 64;
    const float* cvab = cva + (size_t)(b * 4096 + ch * 64) * 256;

    // ph1: LN over cva rows -> A (each wave 8 rows); prefetch all 8 loads first
    {
        float4 vv[8];
#pragma unroll
        for (int i = 0; i < 8; i++)
            vv[i] = *reinterpret_cast<const float4*>(cvab + (size_t)(w * 8 + i) * 256 + l * 4);
#pragma unroll
        for (int i = 0; i < 8; i++) {
            int row = w * 8 + i;
            float4 v = vv[i];
            float s = v.x + v.y + v.z + v.w;
            float q2 = v.x * v.x + v.y * v.y + v.z * v.z + v.w * v.w;
#pragma unroll
            for (int m = 1; m < 64; m <<= 1) { s += __shfl_xor(s, m); q2 += __shfl_xor(q2, m); }
            float mean = s * (1.0f / 256.0f);
            float rstd = rsqrtf(q2 * (1.0f / 256.0f) - mean * mean + 1e-5f);
            bfx4 o;
            o[0] = f2bf((v.x - mean) * rstd);
            o[1] = f2bf((v.y - mean) * rstd);
            o[2] = f2bf((v.z - mean) * rstd);
            o[3] = f2bf((v.w - mean) * rstd);
            *reinterpret_cast<bfx4*>(A + row * 264 + l * 4) = o;
        }
    }
    __syncthreads();  // bar0: cva_hat ready

    // ph2: merged q+k GEMM (shared A-fragment reads), weights streamed from L2
    f32x4 qa[4][2] = {}, ka[4][2] = {};
    {
        const short* wq0 = wt + (size_t)(w * 32 + c) * 256 + g * 8;
        const short* wq1 = wq0 + 16 * 256;
        const short* wk0 = wq0 + 65536;
        const short* wk1 = wq1 + 65536;
#pragma unroll
        for (int ks = 0; ks < 8; ks++) {
            bfx8 af[4];
#pragma unroll
            for (int m = 0; m < 4; m++)
                af[m] = *reinterpret_cast<const bfx8*>(A + (m * 16 + c) * 264 + ks * 32 + g * 8);
            bfx8 q0 = *reinterpret_cast<const bfx8*>(wq0 + ks * 32);
            bfx8 q1 = *reinterpret_cast<const bfx8*>(wq1 + ks * 32);
            bfx8 k0 = *reinterpret_cast<const bfx8*>(wk0 + ks * 32);
            bfx8 k1 = *reinterpret_cast<const bfx8*>(wk1 + ks * 32);
#pragma unroll
            for (int m = 0; m < 4; m++) {
                qa[m][0] = MFMA16(af[m], q0, qa[m][0]);
                qa[m][1] = MFMA16(af[m], q1, qa[m][1]);
                ka[m][0] = MFMA16(af[m], k0, ka[m][0]);
                ka[m][1] = MFMA16(af[m], k1, ka[m][1]);
            }
        }
    }

    // issue x column loads (latency hidden under the two transposes + stats + bar1)
    float xg[32];
#pragma unroll
    for (int i = 0; i < 32; i++) xg[i] = xb[(size_t)(w * 32 + i) * 4096 + l];

    // transpose q through scratch [64 tok][pitch 40] -> qf (B-frag of Q^T)
    bfx8 qf[4];
    {
        float b0 = bb[w * 32 + c], b1 = bb[w * 32 + 16 + c];
#pragma unroll
        for (int m = 0; m < 4; m++)
#pragma unroll
            for (int j = 0; j < 4; j++) {
                S[(m * 16 + g * 4 + j) * 40 + c]      = f2bf(qa[m][0][j] + b0);
                S[(m * 16 + g * 4 + j) * 40 + 16 + c] = f2bf(qa[m][1][j] + b1);
            }
        LGKM0();
#pragma unroll
        for (int np = 0; np < 4; np++)
            qf[np] = *reinterpret_cast<const bfx8*>(S + (np * 16 + c) * 40 + g * 8);
        LGKM0();
    }

    // transpose k -> kf (A-frag of K)
    bfx8 kf[4];
    {
        float b0 = bb[256 + w * 32 + c], b1 = bb[256 + w * 32 + 16 + c];
#pragma unroll
        for (int m = 0; m < 4; m++)
#pragma unroll
            for (int j = 0; j < 4; j++) {
                S[(m * 16 + g * 4 + j) * 40 + c]      = f2bf(ka[m][0][j] + b0);
                S[(m * 16 + g * 4 + j) * 40 + 16 + c] = f2bf(ka[m][1][j] + b1);
            }
        LGKM0();
#pragma unroll
        for (int m = 0; m < 4; m++)
            kf[m] = *reinterpret_cast<const bfx8*>(S + (m * 16 + c) * 40 + g * 8);
        LGKM0();
    }

    // x stats partials (token = l, c-slice = w*32..+32)
    {
        float s = 0.f, q2 = 0.f;
#pragma unroll
        for (int i = 0; i < 32; i++) { s += xg[i]; q2 += xg[i] * xg[i]; }
        red[w][l][0] = s;
        red[w][l][1] = q2;
    }
    __syncthreads();  // bar1: all cva_hat reads done, red ready

    float xmean, xrstd;
    {
        float s = 0.f, q2 = 0.f;
#pragma unroll
        for (int j2 = 0; j2 < 8; j2++) { s += red[j2][l][0]; q2 += red[j2][l][1]; }
        xmean = s * (1.0f / 256.0f);
        xrstd = rsqrtf(q2 * (1.0f / 256.0f) - xmean * xmean + 1e-5f);
    }

    // ph3: xs_hat -> A (row = token l, cols w*32..+32)
#pragma unroll
    for (int i2 = 0; i2 < 4; i2++) {
        bfx8 o;
#pragma unroll
        for (int jj = 0; jj < 8; jj++) o[jj] = f2bf((xg[i2 * 8 + jj] - xmean) * xrstd);
        *reinterpret_cast<bfx8*>(A + l * 264 + w * 32 + i2 * 8) = o;
    }
    __syncthreads();  // bar2: xs_hat ready

    // ph4: v GEMM from A (xs_hat) -> va (C-layout); issued first so weight loads
    // overlap the register-only QK^T/softmax below
    f32x4 va[4][2] = {};
    {
        const short* w0 = wt + 2 * 65536 + (size_t)(w * 32 + c) * 256 + g * 8;
        const short* w1 = w0 + 16 * 256;
#pragma unroll
        for (int ks = 0; ks < 8; ks++) {
            bfx8 af[4];
#pragma unroll
            for (int m = 0; m < 4; m++)
                af[m] = *reinterpret_cast<const bfx8*>(A + (m * 16 + c) * 264 + ks * 32 + g * 8);
            bfx8 v0 = *reinterpret_cast<const bfx8*>(w0 + ks * 32);
            bfx8 v1 = *reinterpret_cast<const bfx8*>(w1 + ks * 32);
#pragma unroll
            for (int m = 0; m < 4; m++) {
                va[m][0] = MFMA16(af[m], v0, va[m][0]);
                va[m][1] = MFMA16(af[m], v1, va[m][1]);
            }
        }
    }

    // QK^T in S^T orientation: sa[m][np] = S^T[key 16m+4g+j][token 16np+c]
    f32x4 sa[4][4] = {};
#pragma unroll
    for (int m = 0; m < 4; m++)
#pragma unroll
        for (int np = 0; np < 4; np++)
            sa[m][np] = MFMA16(kf[m], qf[np], sa[m][np]);

    // softmax over keys (rows of S^T): in-lane + 2 shfls per token tile
    float rs[4];
#pragma unroll
    for (int np = 0; np < 4; np++) {
        float mx = sa[0][np][0];
#pragma unroll
        for (int m = 0; m < 4; m++)
#pragma unroll
            for (int j = 0; j < 4; j++) mx = fmaxf(mx, sa[m][np][j]);
        mx = fmaxf(mx, __shfl_xor(mx, 16));
        mx = fmaxf(mx, __shfl_xor(mx, 32));
        float sum = 0.f;
#pragma unroll
        for (int m = 0; m < 4; m++)
#pragma unroll
            for (int j = 0; j < 4; j++) {
                float e = __expf(sa[m][np][j] - mx);
                sa[m][np][j] = e;
                sum += e;
            }
        sum += __shfl_xor(sum, 16);
        sum += __shfl_xor(sum, 32);
        rs[np] = 1.0f / sum;  // folded into O^T at the end
    }

    // pack P^T (unnormalized, <=1) to bf16 pairs in registers
    unsigned Pp[4][4][2];
#pragma unroll
    for (int m = 0; m < 4; m++)
#pragma unroll
        for (int np = 0; np < 4; np++) {
            Pp[m][np][0] = pk2(sa[m][np][0], sa[m][np][1]);
            Pp[m][np][1] = pk2(sa[m][np][2], sa[m][np][3]);
        }
    __syncthreads();  // bar3: all xs_hat reads done (o_s writes follow)

    // V transpose through scratch [32 d][pitch 72] -> vf (A-frag of V^T), b64-packed
    bfx8 vf[2][2];
    {
        float b0 = bb[512 + w * 32 + c], b1 = bb[512 + w * 32 + 16 + c];
#pragma unroll
        for (int m = 0; m < 4; m++) {
            bfx4 t0, t1;
#pragma unroll
            for (int j = 0; j < 4; j++) {
                t0[j] = f2bf(va[m][0][j] + b0);
                t1[j] = f2bf(va[m][1][j] + b1);
            }
            *reinterpret_cast<bfx4*>(S + c * 72 + m * 16 + g * 4)        = t0;
            *reinterpret_cast<bfx4*>(S + (16 + c) * 72 + m * 16 + g * 4) = t1;
        }
        LGKM0();
#pragma unroll
        for (int ks = 0; ks < 2; ks++)
#pragma unroll
            for (int mD = 0; mD < 2; mD++)
                vf[ks][mD] = *reinterpret_cast<const bfx8*>(S + (mD * 16 + c) * 72 + ks * 32 + g * 8);
        LGKM0();
    }

    // PV: O^T accumulate over two 32-key halves; P^T half through scratch [64][40]
    f32x4 oa[2][4] = {};
#pragma unroll
    for (int ks = 0; ks < 2; ks++) {
#pragma unroll
        for (int m2 = 0; m2 < 2; m2++)
#pragma unroll
            for (int np = 0; np < 4; np++) {
                *reinterpret_cast<unsigned*>(S + (np * 16 + c) * 40 + m2 * 16 + g * 4)     = Pp[ks * 2 + m2][np][0];
                *reinterpret_cast<unsigned*>(S + (np * 16 + c) * 40 + m2 * 16 + g * 4 + 2) = Pp[ks * 2 + m2][np][1];
            }
        LGKM0();
        bfx8 pf[4];
#pragma unroll
        for (int np = 0; np < 4; np++)
            pf[np] = *reinterpret_cast<const bfx8*>(S + (np * 16 + c) * 40 + g * 8);
        LGKM0();
#pragma unroll
        for (int mD = 0; mD < 2; mD++)
#pragma unroll
            for (int np = 0; np < 4; np++)
                oa[mD][np] = MFMA16(vf[ks][mD], pf[np], oa[mD][np]);
    }

    // o_s write (normalize by rs here): A[token][32w + d]
#pragma unroll
    for (int mD = 0; mD < 2; mD++)
#pragma unroll
        for (int np = 0; np < 4; np++) {
            bfx4 o4;
#pragma unroll
            for (int j = 0; j < 4; j++) o4[j] = f2bf(oa[mD][np][j] * rs[np]);
            *reinterpret_cast<bfx4*>(A + (np * 16 + c) * 264 + w * 32 + mD * 16 + g * 4) = o4;
        }
    __syncthreads();  // bar4: o_s ready

    // ph6: projection (wave = 32 output channels) + transposed fp32 store
    {
        f32x4 pa[4][2] = {};
        const short* w0 = wt + 3 * 65536 + (size_t)(w * 32 + c) * 256 + g * 8;
        const short* w1 = w0 + 16 * 256;
#pragma unroll
        for (int ks = 0; ks < 8; ks++) {
            bfx8 af[4];
#pragma unroll
            for (int m = 0; m < 4; m++)
                af[m] = *reinterpret_cast<const bfx8*>(A + (m * 16 + c) * 264 + ks * 32 + g * 8);
            bfx8 p0 = *reinterpret_cast<const bfx8*>(w0 + ks * 32);
            bfx8 p1 = *reinterpret_cast<const bfx8*>(w1 + ks * 32);
#pragma unroll
            for (int m = 0; m < 4; m++) {
                pa[m][0] = MFMA16(af[m], p0, pa[m][0]);
                pa[m][1] = MFMA16(af[m], p1, pa[m][1]);
            }
        }
        float* trw = reinterpret_cast<float*>(S);  // own scratch, 16x65 floats
        float* outb = out + (size_t)b * 1048576 + ch * 64;
#pragma unroll
        for (int p = 0; p < 2; p++) {
            float bvv = bb[768 + w * 32 + p * 16 + c];
#pragma unroll
            for (int m = 0; m < 4; m++)
#pragma unroll
                for (int j = 0; j < 4; j++)
                    trw[c * 65 + m * 16 + g * 4 + j] = pa[m][p][j] + bvv;
            LGKM0();
#pragma unroll
            for (int cl = 0; cl < 16; cl++) {
                int co = w * 32 + p * 16 + cl;
                outb[(size_t)co * 4096 + l] = trw[cl * 65 + l];
            }
            LGKM0();
        }
    }
}

extern "C" void kernel_launch(void* const* d_in, const int* in_sizes, int n_in,
                              void* d_out, int out_size, void* d_ws, size_t ws_size,
                              hipStream_t stream) {
    const float* x   = (const float*)d_in[0];
    const float* cva = (const float*)d_in[1];
    const float* qg  = (const float*)d_in[2];
    const float* qb  = (const float*)d_in[3];
    const float* kg  = (const float*)d_in[4];
    const float* kb  = (const float*)d_in[5];
    const float* vg  = (const float*)d_in[6];
    const float* vb  = (const float*)d_in[7];
    const float* Wq  = (const float*)d_in[8];
    const float* bq  = (const float*)d_in[9];
    const float* Wk  = (const float*)d_in[10];
    const float* bk  = (const float*)d_in[11];
    const float* Wv  = (const float*)d_in[12];
    const float* bv  = (const float*)d_in[13];
    const float* Wp  = (const float*)d_in[14];
    const float* bp  = (const float*)d_in[15];
    float* out = (float*)d_out;
    char* ws = (char*)d_ws;

    short* wt  = (short*)(ws);
    float* bb  = (float*)(ws + 4 * 65536 * sizeof(short));
    float* bbp = bb + 1024;

    prep_w<<<dim3(4, 16), 256, 0, stream>>>(Wq, Wk, Wv, Wp, qg, qb, kg, kb, vg, vb,
                                            wt, bbp);
    prep_b<<<4, 256, 0, stream>>>(bq, bk, bv, bp, bbp, bb);

    mega<<<512, 512, 0, stream>>>(x, cva, wt, bb, out);
}

// Round 7
// 67.076 us; speedup vs baseline: 1.0573x; 1.0573x over previous
//
#include <hip/hip_runtime.h>
#include <hip/hip_bf16.h>

#define NTOK 4096
#define BATCH 8
#define NROWS (BATCH * NTOK)   // 32768

typedef __attribute__((ext_vector_type(8))) short bfx8;
typedef __attribute__((ext_vector_type(4))) short bfx4;
typedef __attribute__((ext_vector_type(4))) float f32x4;

__device__ __forceinline__ short f2bf(float f) {
    unsigned u = __builtin_bit_cast(unsigned, f);
    u += 0x7fffu + ((u >> 16) & 1u);
    return (short)(u >> 16);
}
__device__ __forceinline__ unsigned pk2(float a, float b) {
    return (unsigned)(unsigned short)f2bf(a) | ((unsigned)(unsigned short)f2bf(b) << 16);
}

#define MFMA16(a, b, c) __builtin_amdgcn_mfma_f32_16x16x32_bf16(a, b, c, 0, 0, 0)
#define LGKM0()                                              \
    do {                                                     \
        asm volatile("s_waitcnt lgkmcnt(0)" ::: "memory");   \
        __builtin_amdgcn_sched_barrier(0);                   \
    } while (0)

// ---------------- weight prep: WT[co][ci] = bf16(scale * g[ci] * W[ci][co]) ----------------
__global__ __launch_bounds__(256) void prep_w(
    const float* __restrict__ Wq, const float* __restrict__ Wk,
    const float* __restrict__ Wv, const float* __restrict__ Wp,
    const float* __restrict__ qg, const float* __restrict__ qb,
    const float* __restrict__ kg, const float* __restrict__ kb,
    const float* __restrict__ vg, const float* __restrict__ vb,
    short* __restrict__ wt, float* __restrict__ bbp) {
    int m = blockIdx.x;
    int ci0 = blockIdx.y * 16;
    const float *W, *g, *be;
    float scale = 1.0f;
    if (m == 0)      { W = Wq; g = qg; be = qb; scale = 0.17677669529663687f; }
    else if (m == 1) { W = Wk; g = kg; be = kb; }
    else if (m == 2) { W = Wv; g = vg; be = vb; }
    else             { W = Wp; g = nullptr; be = nullptr; }
    __shared__ float tile[16][257];
    int t = threadIdx.x;
#pragma unroll
    for (int i = 0; i < 16; i++)
        tile[i][t] = W[(size_t)(ci0 + i) * 256 + t];
    __syncthreads();
    float p = 0.f;
    if (be) {
#pragma unroll
        for (int i = 0; i < 16; i++) p += be[ci0 + i] * tile[i][t];
    }
    bbp[(m * 16 + blockIdx.y) * 256 + t] = p;
    short* WT = wt + m * 65536 + t * 256 + ci0;
    bfx8 o0, o1;
#pragma unroll
    for (int j = 0; j < 8; j++) {
        float gv = g ? g[ci0 + j] : 1.0f;
        o0[j] = f2bf(scale * gv * tile[j][t]);
    }
#pragma unroll
    for (int j = 0; j < 8; j++) {
        float gv = g ? g[ci0 + 8 + j] : 1.0f;
        o1[j] = f2bf(scale * gv * tile[8 + j][t]);
    }
    *reinterpret_cast<bfx8*>(WT) = o0;
    *reinterpret_cast<bfx8*>(WT + 8) = o1;
}

__global__ __launch_bounds__(256) void prep_b(
    const float* __restrict__ bq, const float* __restrict__ bk,
    const float* __restrict__ bv, const float* __restrict__ bp,
    const float* __restrict__ bbp, float* __restrict__ bb) {
    int m = blockIdx.x, t = threadIdx.x;
    const float* bias = (m == 0) ? bq : (m == 1) ? bk : (m == 2) ? bv : bp;
    float scale = (m == 0) ? 0.17677669529663687f : 1.0f;
    float s = bias[t];
#pragma unroll
    for (int i = 0; i < 16; i++) s += bbp[(m * 16 + i) * 256 + t];
    bb[m * 256 + t] = scale * s;
}

// ---------------- mega kernel: LN + qkv GEMM + attention + projection ----------------
// 512 blocks (b, chunk) x 512 threads (8 waves; wave = head = 32-col strip).
// Shared A slot (pitch 264): cva_hat -> xs_hat -> o_s.
// Per-wave 5120B scratch: q^T -> k^T -> V^T -> P^T halves.
// Attention in S^T orientation: S^T = mfma(K,Q^T); O^T = mfma(V^T,P^T).
__global__ __launch_bounds__(512, 4) void mega(const float* __restrict__ x,
                                               const float* __restrict__ cva,
                                               const short* __restrict__ wt,
                                               const float* __restrict__ bb,
                                               float* __restrict__ out) {
    int id = blockIdx.x;
    int b = id >> 6, ch = id & 63;
    int t = threadIdx.x, w = t >> 6, l = t & 63, c = l & 15, g = l >> 4;

    __shared__ short A[64 * 264];       // 33792 B
    __shared__ short scr_[8][2560];     // 40960 B (5120 B per wave)
    __shared__ float red[8][64][2];     // 4096 B
    short* S = scr_[w];

    const float* xb   = x + (size_t)b * 1048576 + ch * 64;
    const float* cvab = cva + (size_t)(b * 4096 + ch * 64) * 256;

    // ph1: LN over cva rows -> A. 4 rows/pass, 16 lanes/row, 16 floats/lane:
    // in-lane 16-sum + 4 shuffle levels (xor<=8 lowers to DPP, not LDS).
    {
        int r16 = l >> 4;  // row within pass-quad
        float fv[2][16];
#pragma unroll
        for (int p2 = 0; p2 < 2; p2++) {
            int row = w * 8 + p2 * 4 + r16;
#pragma unroll
            for (int i = 0; i < 4; i++) {
                float4 v4 = *reinterpret_cast<const float4*>(
                    cvab + (size_t)row * 256 + c * 16 + i * 4);
                fv[p2][i * 4 + 0] = v4.x;
                fv[p2][i * 4 + 1] = v4.y;
                fv[p2][i * 4 + 2] = v4.z;
                fv[p2][i * 4 + 3] = v4.w;
            }
        }
#pragma unroll
        for (int p2 = 0; p2 < 2; p2++) {
            int row = w * 8 + p2 * 4 + r16;
            float s = 0.f, q2 = 0.f;
#pragma unroll
            for (int i = 0; i < 16; i++) {
                s += fv[p2][i];
                q2 += fv[p2][i] * fv[p2][i];
            }
            s += __shfl_xor(s, 1);  q2 += __shfl_xor(q2, 1);
            s += __shfl_xor(s, 2);  q2 += __shfl_xor(q2, 2);
            s += __shfl_xor(s, 4);  q2 += __shfl_xor(q2, 4);
            s += __shfl_xor(s, 8);  q2 += __shfl_xor(q2, 8);
            float mean = s * (1.0f / 256.0f);
            float rstd = rsqrtf(q2 * (1.0f / 256.0f) - mean * mean + 1e-5f);
            bfx8 o0, o1;
#pragma unroll
            for (int jj = 0; jj < 8; jj++) {
                o0[jj] = f2bf((fv[p2][jj] - mean) * rstd);
                o1[jj] = f2bf((fv[p2][8 + jj] - mean) * rstd);
            }
            *reinterpret_cast<bfx8*>(A + row * 264 + c * 16) = o0;
            *reinterpret_cast<bfx8*>(A + row * 264 + c * 16 + 8) = o1;
        }
    }
    __syncthreads();  // bar0: cva_hat ready

    // ph2: merged q+k GEMM (shared A-fragment reads), weights streamed from L2
    f32x4 qa[4][2] = {}, ka[4][2] = {};
    {
        const short* wq0 = wt + (size_t)(w * 32 + c) * 256 + g * 8;
        const short* wq1 = wq0 + 16 * 256;
        const short* wk0 = wq0 + 65536;
        const short* wk1 = wq1 + 65536;
#pragma unroll
        for (int ks = 0; ks < 8; ks++) {
            bfx8 af[4];
#pragma unroll
            for (int m = 0; m < 4; m++)
                af[m] = *reinterpret_cast<const bfx8*>(A + (m * 16 + c) * 264 + ks * 32 + g * 8);
            bfx8 q0 = *reinterpret_cast<const bfx8*>(wq0 + ks * 32);
            bfx8 q1 = *reinterpret_cast<const bfx8*>(wq1 + ks * 32);
            bfx8 k0 = *reinterpret_cast<const bfx8*>(wk0 + ks * 32);
            bfx8 k1 = *reinterpret_cast<const bfx8*>(wk1 + ks * 32);
#pragma unroll
            for (int m = 0; m < 4; m++) {
                qa[m][0] = MFMA16(af[m], q0, qa[m][0]);
                qa[m][1] = MFMA16(af[m], q1, qa[m][1]);
                ka[m][0] = MFMA16(af[m], k0, ka[m][0]);
                ka[m][1] = MFMA16(af[m], k1, ka[m][1]);
            }
        }
    }

    // issue x column loads (latency hidden under the two transposes + stats + bar1)
    float xg[32];
#pragma unroll
    for (int i = 0; i < 32; i++) xg[i] = xb[(size_t)(w * 32 + i) * 4096 + l];

    // transpose q through scratch [64 tok][pitch 40] -> qf (B-frag of Q^T)
    bfx8 qf[4];
    {
        float b0 = bb[w * 32 + c], b1 = bb[w * 32 + 16 + c];
#pragma unroll
        for (int m = 0; m < 4; m++)
#pragma unroll
            for (int j = 0; j < 4; j++) {
                S[(m * 16 + g * 4 + j) * 40 + c]      = f2bf(qa[m][0][j] + b0);
                S[(m * 16 + g * 4 + j) * 40 + 16 + c] = f2bf(qa[m][1][j] + b1);
            }
        LGKM0();
#pragma unroll
        for (int np = 0; np < 4; np++)
            qf[np] = *reinterpret_cast<const bfx8*>(S + (np * 16 + c) * 40 + g * 8);
        LGKM0();
    }

    // transpose k -> kf (A-frag of K)
    bfx8 kf[4];
    {
        float b0 = bb[256 + w * 32 + c], b1 = bb[256 + w * 32 + 16 + c];
#pragma unroll
        for (int m = 0; m < 4; m++)
#pragma unroll
            for (int j = 0; j < 4; j++) {
                S[(m * 16 + g * 4 + j) * 40 + c]      = f2bf(ka[m][0][j] + b0);
                S[(m * 16 + g * 4 + j) * 40 + 16 + c] = f2bf(ka[m][1][j] + b1);
            }
        LGKM0();
#pragma unroll
        for (int m = 0; m < 4; m++)
            kf[m] = *reinterpret_cast<const bfx8*>(S + (m * 16 + c) * 40 + g * 8);
        LGKM0();
    }

    // x stats partials (token = l, c-slice = w*32..+32)
    {
        float s = 0.f, q2 = 0.f;
#pragma unroll
        for (int i = 0; i < 32; i++) { s += xg[i]; q2 += xg[i] * xg[i]; }
        red[w][l][0] = s;
        red[w][l][1] = q2;
    }
    __syncthreads();  // bar1: all cva_hat reads done, red ready

    float xmean, xrstd;
    {
        float s = 0.f, q2 = 0.f;
#pragma unroll
        for (int j2 = 0; j2 < 8; j2++) { s += red[j2][l][0]; q2 += red[j2][l][1]; }
        xmean = s * (1.0f / 256.0f);
        xrstd = rsqrtf(q2 * (1.0f / 256.0f) - xmean * xmean + 1e-5f);
    }

    // ph3: xs_hat -> A (row = token l, cols w*32..+32)
#pragma unroll
    for (int i2 = 0; i2 < 4; i2++) {
        bfx8 o;
#pragma unroll
        for (int jj = 0; jj < 8; jj++) o[jj] = f2bf((xg[i2 * 8 + jj] - xmean) * xrstd);
        *reinterpret_cast<bfx8*>(A + l * 264 + w * 32 + i2 * 8) = o;
    }
    __syncthreads();  // bar2: xs_hat ready

    // QK^T in S^T orientation (register-only inputs, issues immediately):
    // sa[m][np] = S^T[key 16m+4g+j][token 16np+c]
    f32x4 sa[4][4] = {};
#pragma unroll
    for (int m = 0; m < 4; m++)
#pragma unroll
        for (int np = 0; np < 4; np++)
            sa[m][np] = MFMA16(kf[m], qf[np], sa[m][np]);

    // softmax over keys (rows of S^T): in-lane + 2 shfls per token tile
    float rs[4];
#pragma unroll
    for (int np = 0; np < 4; np++) {
        float mx = sa[0][np][0];
#pragma unroll
        for (int m = 0; m < 4; m++)
#pragma unroll
            for (int j = 0; j < 4; j++) mx = fmaxf(mx, sa[m][np][j]);
        mx = fmaxf(mx, __shfl_xor(mx, 16));
        mx = fmaxf(mx, __shfl_xor(mx, 32));
        float sum = 0.f;
#pragma unroll
        for (int m = 0; m < 4; m++)
#pragma unroll
            for (int j = 0; j < 4; j++) {
                float e = __expf(sa[m][np][j] - mx);
                sa[m][np][j] = e;
                sum += e;
            }
        sum += __shfl_xor(sum, 16);
        sum += __shfl_xor(sum, 32);
        rs[np] = 1.0f / sum;  // folded into O^T at the end
    }

    // pack P^T (unnormalized, <=1) to bf16 pairs in registers
    unsigned Pp[4][4][2];
#pragma unroll
    for (int m = 0; m < 4; m++)
#pragma unroll
        for (int np = 0; np < 4; np++) {
            Pp[m][np][0] = pk2(sa[m][np][0], sa[m][np][1]);
            Pp[m][np][1] = pk2(sa[m][np][2], sa[m][np][3]);
        }

    // ph4: v GEMM from A (xs_hat) -> va (C-layout)
    f32x4 va[4][2] = {};
    {
        const short* w0 = wt + 2 * 65536 + (size_t)(w * 32 + c) * 256 + g * 8;
        const short* w1 = w0 + 16 * 256;
#pragma unroll
        for (int ks = 0; ks < 8; ks++) {
            bfx8 af[4];
#pragma unroll
            for (int m = 0; m < 4; m++)
                af[m] = *reinterpret_cast<const bfx8*>(A + (m * 16 + c) * 264 + ks * 32 + g * 8);
            bfx8 v0 = *reinterpret_cast<const bfx8*>(w0 + ks * 32);
            bfx8 v1 = *reinterpret_cast<const bfx8*>(w1 + ks * 32);
#pragma unroll
            for (int m = 0; m < 4; m++) {
                va[m][0] = MFMA16(af[m], v0, va[m][0]);
                va[m][1] = MFMA16(af[m], v1, va[m][1]);
            }
        }
    }
    __syncthreads();  // bar3: all xs_hat reads done (o_s writes follow)

    // V transpose through scratch [32 d][pitch 72] -> vf (A-frag of V^T), b64-packed
    bfx8 vf[2][2];
    {
        float b0 = bb[512 + w * 32 + c], b1 = bb[512 + w * 32 + 16 + c];
#pragma unroll
        for (int m = 0; m < 4; m++) {
            bfx4 t0, t1;
#pragma unroll
            for (int j = 0; j < 4; j++) {
                t0[j] = f2bf(va[m][0][j] + b0);
                t1[j] = f2bf(va[m][1][j] + b1);
            }
            *reinterpret_cast<bfx4*>(S + c * 72 + m * 16 + g * 4)        = t0;
            *reinterpret_cast<bfx4*>(S + (16 + c) * 72 + m * 16 + g * 4) = t1;
        }
        LGKM0();
#pragma unroll
        for (int ks = 0; ks < 2; ks++)
#pragma unroll
            for (int mD = 0; mD < 2; mD++)
                vf[ks][mD] = *reinterpret_cast<const bfx8*>(S + (mD * 16 + c) * 72 + ks * 32 + g * 8);
        LGKM0();
    }

    // PV: O^T accumulate over two 32-key halves; P^T half through scratch [64][40]
    f32x4 oa[2][4] = {};
#pragma unroll
    for (int ks = 0; ks < 2; ks++) {
#pragma unroll
        for (int m2 = 0; m2 < 2; m2++)
#pragma unroll
            for (int np = 0; np < 4; np++) {
                *reinterpret_cast<unsigned*>(S + (np * 16 + c) * 40 + m2 * 16 + g * 4)     = Pp[ks * 2 + m2][np][0];
                *reinterpret_cast<unsigned*>(S + (np * 16 + c) * 40 + m2 * 16 + g * 4 + 2) = Pp[ks * 2 + m2][np][1];
            }
        LGKM0();
        bfx8 pf[4];
#pragma unroll
        for (int np = 0; np < 4; np++)
            pf[np] = *reinterpret_cast<const bfx8*>(S + (np * 16 + c) * 40 + g * 8);
        LGKM0();
#pragma unroll
        for (int mD = 0; mD < 2; mD++)
#pragma unroll
            for (int np = 0; np < 4; np++)
                oa[mD][np] = MFMA16(vf[ks][mD], pf[np], oa[mD][np]);
    }

    // o_s write (normalize by rs here): A[token][32w + d]
#pragma unroll
    for (int mD = 0; mD < 2; mD++)
#pragma unroll
        for (int np = 0; np < 4; np++) {
            bfx4 o4;
#pragma unroll
            for (int j = 0; j < 4; j++) o4[j] = f2bf(oa[mD][np][j] * rs[np]);
            *reinterpret_cast<bfx4*>(A + (np * 16 + c) * 264 + w * 32 + mD * 16 + g * 4) = o4;
        }
    __syncthreads();  // bar4: o_s ready

    // ph6: projection (wave = 32 output channels) + DIRECT C-layout fp32 stores:
    // lane (c,g) holds tokens m*16+g*4..+3 for channel w*32+p*16+c -> dwordx4
    {
        f32x4 pa[4][2] = {};
        const short* w0 = wt + 3 * 65536 + (size_t)(w * 32 + c) * 256 + g * 8;
        const short* w1 = w0 + 16 * 256;
#pragma unroll
        for (int ks = 0; ks < 8; ks++) {
            bfx8 af[4];
#pragma unroll
            for (int m = 0; m < 4; m++)
                af[m] = *reinterpret_cast<const bfx8*>(A + (m * 16 + c) * 264 + ks * 32 + g * 8);
            bfx8 p0 = *reinterpret_cast<const bfx8*>(w0 + ks * 32);
            bfx8 p1 = *reinterpret_cast<const bfx8*>(w1 + ks * 32);
#pragma unroll
            for (int m = 0; m < 4; m++) {
                pa[m][0] = MFMA16(af[m], p0, pa[m][0]);
                pa[m][1] = MFMA16(af[m], p1, pa[m][1]);
            }
        }
        float* outb = out + (size_t)b * 1048576 + ch * 64;
#pragma unroll
        for (int p = 0; p < 2; p++) {
            int co = w * 32 + p * 16 + c;
            float bvv = bb[768 + co];
            float* op = outb + (size_t)co * 4096 + g * 4;
#pragma unroll
            for (int m = 0; m < 4; m++) {
                float4 st;
                st.x = pa[m][p][0] + bvv;
                st.y = pa[m][p][1] + bvv;
                st.z = pa[m][p][2] + bvv;
                st.w = pa[m][p][3] + bvv;
                *reinterpret_cast<float4*>(op + m * 16) = st;
            }
        }
    }
}

extern "C" void kernel_launch(void* const* d_in, const int* in_sizes, int n_in,
                              void* d_out, int out_size, void* d_ws, size_t ws_size,
                              hipStream_t stream) {
    const float* x   = (const float*)d_in[0];
    const float* cva = (const float*)d_in[1];
    const float* qg  = (const float*)d_in[2];
    const float* qb  = (const float*)d_in[3];
    const float* kg  = (const float*)d_in[4];
    const float* kb  = (const float*)d_in[5];
    const float* vg  = (const float*)d_in[6];
    const float* vb  = (const float*)d_in[7];
    const float* Wq  = (const float*)d_in[8];
    const float* bq  = (const float*)d_in[9];
    const float* Wk  = (const float*)d_in[10];
    const float* bk  = (const float*)d_in[11];
    const float* Wv  = (const float*)d_in[12];
    const float* bv  = (const float*)d_in[13];
    const float* Wp  = (const float*)d_in[14];
    const float* bp  = (const float*)d_in[15];
    float* out = (float*)d_out;
    char* ws = (char*)d_ws;

    short* wt  = (short*)(ws);
    float* bb  = (float*)(ws + 4 * 65536 * sizeof(short));
    float* bbp = bb + 1024;

    prep_w<<<dim3(4, 16), 256, 0, stream>>>(Wq, Wk, Wv, Wp, qg, qb, kg, kb, vg, vb,
                                            wt, bbp);
    prep_b<<<4, 256, 0, stream>>>(bq, bk, bv, bp, bbp, bb);

    mega<<<512, 512, 0, stream>>>(x, cva, wt, bb, out);
}